// Round 6
// baseline (95.042 us; speedup 1.0000x reference)
//
#include <hip/hip_runtime.h>

// CondInst dynamic mask head, fused: per-instance MLP (10->8->8->1, x2 heads)
// + aligned_bilinear x2 upsample + sigmoid.
// mask_feats (2,8,200,200) f32, params (128,169) f32 x2, locs (128,2) f32,
// im_inds/fpn_levels int32, stride scalar int (=8).
// Output: 2 x (128,1,400,400) f32 concat flat.

#define BLOCK 256
#define Hh 200
#define Ww 200
#define NP 169
#define TH 25      // output rows per tile
#define MAXR 14    // max head rows needed per tile (factor=2)
#define OW 400
#define OH 400
#define PSTR 224   // per-head packed-param stride (floats), 16B-aligned

typedef float f32x4 __attribute__((ext_vector_type(4)));
typedef float f32x2 __attribute__((ext_vector_type(2)));

__device__ __forceinline__ f32x2 splat2(float v) { f32x2 r; r.x = v; r.y = v; return r; }
__device__ __forceinline__ f32x2 pkfma(f32x2 a, f32x2 b, f32x2 c) {
    return __builtin_elementwise_fma(a, b, c);
}

// Load the 10-channel input for one 4-px chunk. x[ch][pair]: pair0 = px{0,1}, pair1 = px{2,3}.
__device__ __forceinline__ void load_x(
    int c, int r_begin, const float* __restrict__ fbase,
    float ixl, float iyl, float inv_soi, int s, int half,
    f32x2 (&x)[10][2])
{
    const int lr = c / (Ww / 4);
    const int c4 = (c - lr * (Ww / 4)) * 4;
    const int r  = r_begin + lr;
    const float ry   = (iyl - (float)(r * s + half)) * inv_soi;
    const float step = -(float)s * inv_soi;
    const float cx0  = (ixl - (float)(c4 * s + half)) * inv_soi;
    x[0][0].x = cx0;            x[0][0].y = cx0 + step;
    x[0][1].x = cx0 + 2*step;   x[0][1].y = cx0 + 3*step;
    x[1][0] = splat2(ry);       x[1][1] = x[1][0];
    const float* fp = fbase + r * Ww + c4;
    #pragma unroll
    for (int ch = 0; ch < 8; ch++) {
        const f32x4 f = *(const f32x4*)(fp + ch * (Hh * Ww));
        x[2 + ch][0].x = f.x; x[2 + ch][0].y = f.y;
        x[2 + ch][1].x = f.z; x[2 + ch][1].y = f.w;
    }
}

// One head's 3-layer MLP on one (TWO=false) or two (TWO=true) 4-px chunks,
// weights read once per pass from packed LDS (pure b128 reads).
template<bool TWO>
__device__ __forceinline__ void mlp_head(
    const float* __restrict__ P,
    const f32x2 (&xA)[10][2], const f32x2 (&xB)[10][2],
    f32x2 (&oA)[2], f32x2 (&oB)[2])
{
    const f32x2 zero = splat2(0.0f);

    f32x2 h1A[8][2], h1B[8][2];
    #pragma unroll
    for (int o = 0; o < 8; o++) {
        const f32x4 wa = *(const f32x4*)(P + o * 16);
        const f32x4 wb = *(const f32x4*)(P + o * 16 + 4);
        const f32x4 wc = *(const f32x4*)(P + o * 16 + 8);   // w8, w9, bias, pad
        #pragma unroll
        for (int p = 0; p < 2; p++) {
            f32x2 a = splat2(wc.z);
            a = pkfma(splat2(wa.x), xA[0][p], a);
            a = pkfma(splat2(wa.y), xA[1][p], a);
            a = pkfma(splat2(wa.z), xA[2][p], a);
            a = pkfma(splat2(wa.w), xA[3][p], a);
            a = pkfma(splat2(wb.x), xA[4][p], a);
            a = pkfma(splat2(wb.y), xA[5][p], a);
            a = pkfma(splat2(wb.z), xA[6][p], a);
            a = pkfma(splat2(wb.w), xA[7][p], a);
            a = pkfma(splat2(wc.x), xA[8][p], a);
            a = pkfma(splat2(wc.y), xA[9][p], a);
            h1A[o][p] = __builtin_elementwise_max(a, zero);
            if (TWO) {
                f32x2 b = splat2(wc.z);
                b = pkfma(splat2(wa.x), xB[0][p], b);
                b = pkfma(splat2(wa.y), xB[1][p], b);
                b = pkfma(splat2(wa.z), xB[2][p], b);
                b = pkfma(splat2(wa.w), xB[3][p], b);
                b = pkfma(splat2(wb.x), xB[4][p], b);
                b = pkfma(splat2(wb.y), xB[5][p], b);
                b = pkfma(splat2(wb.z), xB[6][p], b);
                b = pkfma(splat2(wb.w), xB[7][p], b);
                b = pkfma(splat2(wc.x), xB[8][p], b);
                b = pkfma(splat2(wc.y), xB[9][p], b);
                h1B[o][p] = __builtin_elementwise_max(b, zero);
            }
        }
    }

    // L2 biases: one pair of b128 reads per head pass
    const f32x4 blo = *(const f32x4*)(P + 192);
    const f32x4 bhi = *(const f32x4*)(P + 196);
    const float b1v[8] = {blo.x, blo.y, blo.z, blo.w, bhi.x, bhi.y, bhi.z, bhi.w};

    f32x2 h2A[8][2], h2B[8][2];
    #pragma unroll
    for (int o = 0; o < 8; o++) {
        const f32x4 wa = *(const f32x4*)(P + 128 + o * 8);
        const f32x4 wb = *(const f32x4*)(P + 128 + o * 8 + 4);
        #pragma unroll
        for (int p = 0; p < 2; p++) {
            f32x2 a = splat2(b1v[o]);
            a = pkfma(splat2(wa.x), h1A[0][p], a);
            a = pkfma(splat2(wa.y), h1A[1][p], a);
            a = pkfma(splat2(wa.z), h1A[2][p], a);
            a = pkfma(splat2(wa.w), h1A[3][p], a);
            a = pkfma(splat2(wb.x), h1A[4][p], a);
            a = pkfma(splat2(wb.y), h1A[5][p], a);
            a = pkfma(splat2(wb.z), h1A[6][p], a);
            a = pkfma(splat2(wb.w), h1A[7][p], a);
            h2A[o][p] = __builtin_elementwise_max(a, zero);
            if (TWO) {
                f32x2 b = splat2(b1v[o]);
                b = pkfma(splat2(wa.x), h1B[0][p], b);
                b = pkfma(splat2(wa.y), h1B[1][p], b);
                b = pkfma(splat2(wa.z), h1B[2][p], b);
                b = pkfma(splat2(wa.w), h1B[3][p], b);
                b = pkfma(splat2(wb.x), h1B[4][p], b);
                b = pkfma(splat2(wb.y), h1B[5][p], b);
                b = pkfma(splat2(wb.z), h1B[6][p], b);
                b = pkfma(splat2(wb.w), h1B[7][p], b);
                h2B[o][p] = __builtin_elementwise_max(b, zero);
            }
        }
    }

    {
        const f32x4 wa = *(const f32x4*)(P + 200);
        const f32x4 wb = *(const f32x4*)(P + 204);
        const float b2 = P[208];
        #pragma unroll
        for (int p = 0; p < 2; p++) {
            f32x2 a = splat2(b2);
            a = pkfma(splat2(wa.x), h2A[0][p], a);
            a = pkfma(splat2(wa.y), h2A[1][p], a);
            a = pkfma(splat2(wa.z), h2A[2][p], a);
            a = pkfma(splat2(wa.w), h2A[3][p], a);
            a = pkfma(splat2(wb.x), h2A[4][p], a);
            a = pkfma(splat2(wb.y), h2A[5][p], a);
            a = pkfma(splat2(wb.z), h2A[6][p], a);
            a = pkfma(splat2(wb.w), h2A[7][p], a);
            oA[p] = a;
            if (TWO) {
                f32x2 b = splat2(b2);
                b = pkfma(splat2(wa.x), h2B[0][p], b);
                b = pkfma(splat2(wa.y), h2B[1][p], b);
                b = pkfma(splat2(wa.z), h2B[2][p], b);
                b = pkfma(splat2(wa.w), h2B[3][p], b);
                b = pkfma(splat2(wb.x), h2B[4][p], b);
                b = pkfma(splat2(wb.y), h2B[5][p], b);
                b = pkfma(splat2(wb.z), h2B[6][p], b);
                b = pkfma(splat2(wb.w), h2B[7][p], b);
                oB[p] = b;
            }
        }
    }
}

__global__ __launch_bounds__(BLOCK) void dmh_fused(
    const float* __restrict__ mask_feats,
    const float* __restrict__ mparams,
    const float* __restrict__ bparams,
    const float* __restrict__ ilocs,
    const int*   __restrict__ im_inds,
    const int*   __restrict__ fpn_levels,
    const int*   __restrict__ stride_p,
    float* __restrict__ out,
    int n_inst)
{
    // packed per-head layout (floats, all rows 16B-aligned):
    //   L1: o*16 + [0..9] = w, o*16+10 = bias (read as 3 b128/o)
    //   L2: 128 + o*8 = w (2 b128/o); biases at 192..199 (2 b128/head)
    //   L3: 200..207 = w (2 b128), 208 = bias
    __shared__ __align__(16) float s_par[2 * PSTR];
    __shared__ __align__(16) float s_m[2][MAXR][Ww];

    const int tid  = threadIdx.x;
    const int tile = blockIdx.x;   // 0..15
    const int inst = blockIdx.y;

    for (int j = tid; j < 2 * NP; j += BLOCK) {
        const int head = (j < NP) ? 0 : 1;
        const int k = j - head * NP;
        const float v = head ? bparams[inst * NP + k] : mparams[inst * NP + k];
        int dst;
        if      (k < 80)  dst = (k / 10) * 16 + (k % 10);
        else if (k < 144) dst = 128 + (k - 80);
        else if (k < 152) dst = 200 + (k - 144);
        else if (k < 160) dst = (k - 152) * 16 + 10;
        else if (k < 168) dst = 192 + (k - 160);
        else              dst = 208;
        s_par[head * PSTR + dst] = v;
    }

    const int   s    = stride_p[0];       // 8
    const int   half = s >> 1;
    const int   im   = im_inds[inst];
    const int   lvl  = fpn_levels[inst];
    const float inv_soi = 1.0f / (float)(64 << lvl);  // SOI = 64*2^lvl exactly
    const float ixl = ilocs[inst * 2 + 0];
    const float iyl = ilocs[inst * 2 + 1];

    const int i0 = tile * TH;
    const int r_begin = ((i0 > 0) ? (i0 - 1) : 0) >> 1;
    int r_end = ((i0 + TH - 2) >> 1) + 1;
    if (r_end > Hh - 1) r_end = Hh - 1;
    const int nrows = r_end - r_begin + 1;   // 13 or 14

    __syncthreads();

    // ---------- Phase A: head MLP at 200-res into LDS ----------
    const float* fbase = mask_feats + (size_t)im * 8 * Hh * Ww;
    const int ntask = (nrows * Ww) >> 2;     // 650 or 700 4-px chunks

    // pass 0: chunks tid and tid+256 (always valid: 511 < 650)
    {
        asm volatile("" ::: "memory");   // re-read weights from LDS this pass
        f32x2 xA[10][2], xB[10][2];
        load_x(tid,       r_begin, fbase, ixl, iyl, inv_soi, s, half, xA);
        load_x(tid + 256, r_begin, fbase, ixl, iyl, inv_soi, s, half, xB);
        #pragma unroll 1
        for (int head = 0; head < 2; head++) {
            f32x2 oA[2], oB[2];
            mlp_head<true>(s_par + head * PSTR, xA, xB, oA, oB);
            {
                const int lr = tid / (Ww / 4);
                const int c4 = (tid - lr * (Ww / 4)) * 4;
                f32x4 r; r.x = oA[0].x; r.y = oA[0].y; r.z = oA[1].x; r.w = oA[1].y;
                *(f32x4*)(&s_m[head][lr][c4]) = r;
            }
            {
                const int c2 = tid + 256;
                const int lr = c2 / (Ww / 4);
                const int c4 = (c2 - lr * (Ww / 4)) * 4;
                f32x4 r; r.x = oB[0].x; r.y = oB[0].y; r.z = oB[1].x; r.w = oB[1].y;
                *(f32x4*)(&s_m[head][lr][c4]) = r;
            }
        }
    }
    // pass 1: chunk tid+512 (valid for tid < ntask-512)
    {
        const int c = tid + 512;
        if (c < ntask) {
            asm volatile("" ::: "memory");
            f32x2 xA[10][2];
            load_x(c, r_begin, fbase, ixl, iyl, inv_soi, s, half, xA);
            #pragma unroll 1
            for (int head = 0; head < 2; head++) {
                f32x2 oA[2], oB[2];
                mlp_head<false>(s_par + head * PSTR, xA, xA, oA, oB);
                const int lr = c / (Ww / 4);
                const int c4 = (c - lr * (Ww / 4)) * 4;
                f32x4 r; r.x = oA[0].x; r.y = oA[0].y; r.z = oA[1].x; r.w = oA[1].y;
                *(f32x4*)(&s_m[head][lr][c4]) = r;
            }
        }
    }

    __syncthreads();

    // ---------- Phase B: aligned_bilinear x2 + sigmoid ----------
    // One task = 8 output px from one aligned ds_read_b128 per source row
    // (conflict-free) + 1 guarded scalar left-neighbor.
    float* out0 = out + (size_t)inst * (OH * OW) + (size_t)i0 * OW;
    float* out1 = out0 + (size_t)n_inst * (OH * OW);

    const int NU = OW / 8;            // 50 groups per output row
    const int ntaskb = TH * NU;       // 1250
    for (int t = tid; t < ntaskb; t += BLOCK) {
        const int row = t / NU;
        const int u   = t - row * NU;
        const int i   = i0 + row;
        const int ip  = (i > 0) ? (i - 1) : 0;
        const int y0  = ip >> 1;
        const float wy = (ip & 1) ? 0.5f : 0.0f;
        const int lr0 = y0 - r_begin;
        const int r1c = (y0 + 1 <= Hh - 1) ? (y0 + 1) : (Hh - 1);
        const int lr1 = r1c - r_begin;

        #pragma unroll
        for (int head = 0; head < 2; head++) {
            const f32x4 A0 = *(const f32x4*)(&s_m[head][lr0][4 * u]);
            const f32x4 A1 = *(const f32x4*)(&s_m[head][lr1][4 * u]);
            float p0 = 0.0f, p1 = 0.0f;
            if (u > 0) {
                p0 = s_m[head][lr0][4 * u - 1];
                p1 = s_m[head][lr1][4 * u - 1];
            }
            f32x4 B;
            B.x = A0.x + (A1.x - A0.x) * wy;
            B.y = A0.y + (A1.y - A0.y) * wy;
            B.z = A0.z + (A1.z - A0.z) * wy;
            B.w = A0.w + (A1.w - A0.w) * wy;
            const float PB = p0 + (p1 - p0) * wy;

            float o[8];
            o[0] = (u > 0) ? 0.5f * (PB + B.x) : B.x;
            o[1] = B.x;
            o[2] = 0.5f * (B.x + B.y);
            o[3] = B.y;
            o[4] = 0.5f * (B.y + B.z);
            o[5] = B.z;
            o[6] = 0.5f * (B.z + B.w);
            o[7] = B.w;

            f32x4 lo, hi;
            #pragma unroll
            for (int k = 0; k < 4; k++) lo[k] = 1.0f / (1.0f + __expf(-o[k]));
            #pragma unroll
            for (int k = 0; k < 4; k++) hi[k] = 1.0f / (1.0f + __expf(-o[4 + k]));

            float* dst = (head ? out1 : out0) + row * OW + 8 * u;
            __builtin_nontemporal_store(lo, (f32x4*)dst);
            __builtin_nontemporal_store(hi, (f32x4*)(dst + 4));
        }
    }
}

extern "C" void kernel_launch(void* const* d_in, const int* in_sizes, int n_in,
                              void* d_out, int out_size, void* d_ws, size_t ws_size,
                              hipStream_t stream) {
    const float* mask_feats = (const float*)d_in[0];
    const float* mparams    = (const float*)d_in[1];
    const float* bparams    = (const float*)d_in[2];
    const float* ilocs      = (const float*)d_in[3];
    const int*   im_inds    = (const int*)d_in[4];
    const int*   fpn_levels = (const int*)d_in[5];
    const int*   stride_p   = (const int*)d_in[6];
    float* out = (float*)d_out;

    const int n_inst = in_sizes[1] / NP;      // 128
    dim3 grid(OH / TH, n_inst);               // (16, 128)
    dim3 block(BLOCK);
    hipLaunchKernelGGL(dmh_fused, grid, block, 0, stream,
                       mask_feats, mparams, bparams, ilocs,
                       im_inds, fpn_levels, stride_p, out, n_inst);
}

// Round 7
// 78.669 us; speedup vs baseline: 1.2081x; 1.2081x over previous
//
#include <hip/hip_runtime.h>

// CondInst dynamic mask head, fused: per-instance MLP (10->8->8->1, x2 heads)
// + aligned_bilinear x2 upsample + sigmoid.
// mask_feats (2,8,200,200) f32, params (128,169) f32 x2, locs (128,2) f32,
// im_inds/fpn_levels int32, stride scalar int (=8).
// Output: 2 x (128,1,400,400) f32 concat flat.
//
// Weights are block-uniform -> prologue kernel duplicates each weight into
// {w,w} 64-bit slots in d_ws so the main kernel reads them via s_load (scalar
// cache) and feeds SGPR pairs straight into v_pk_fma_f32. Phase A does ZERO
// LDS reads; LDS holds only the 200-res mask tile for the upsample.

#define BLOCK 256
#define Hh 200
#define Ww 200
#define NP 169
#define TH 25      // output rows per tile
#define MAXR 14    // max head rows needed per tile (factor=2)
#define OW 400
#define OH 400
#define HSTR 384   // per-(inst,head) duplicated-param stride (floats)

typedef float f32x4 __attribute__((ext_vector_type(4)));
typedef float f32x2 __attribute__((ext_vector_type(2)));

__device__ __forceinline__ f32x2 splat2(float v) { f32x2 r; r.x = v; r.y = v; return r; }
__device__ __forceinline__ f32x2 pkfma(f32x2 a, f32x2 b, f32x2 c) {
    return __builtin_elementwise_fma(a, b, c);
}

// ---- prologue: repack params into duplicated pk-friendly layout in ws ----
// per (inst, head), HSTR floats:
//   L1 row o (o=0..7) at o*24:   {w,w} x10 (j=0..9), bias dup at +20
//   L2 row o at 192 + o*20:      {w,w} x8,  bias dup at +16
//   L3 row  at 352:              {w,w} x8,  bias dup at +16
__global__ __launch_bounds__(BLOCK) void repack_params(
    const float* __restrict__ mparams,
    const float* __restrict__ bparams,
    float* __restrict__ wsf)
{
    const int inst = blockIdx.x;
    const int t = threadIdx.x;
    #pragma unroll
    for (int head = 0; head < 2; head++) {
        if (t < NP) {
            const float v = (head ? bparams : mparams)[inst * NP + t];
            const int k = t;
            int dst;
            if      (k < 80)  { const int o = k / 10;       dst = o * 24 + 2 * (k - 10 * o); }
            else if (k < 144) { const int kk = k - 80;      dst = 192 + (kk >> 3) * 20 + 2 * (kk & 7); }
            else if (k < 152) { dst = 352 + 2 * (k - 144); }
            else if (k < 160) { dst = (k - 152) * 24 + 20; }
            else if (k < 168) { dst = 192 + (k - 160) * 20 + 16; }
            else              { dst = 352 + 16; }
            float* p = wsf + (size_t)(inst * 2 + head) * HSTR + dst;
            p[0] = v; p[1] = v;
        }
    }
}

__global__ __launch_bounds__(BLOCK, 3) void dmh_fused(
    const float* __restrict__ mask_feats,
    const float* __restrict__ wsf,
    const float* __restrict__ ilocs,
    const int*   __restrict__ im_inds,
    const int*   __restrict__ fpn_levels,
    const int*   __restrict__ stride_p,
    float* __restrict__ out,
    int n_inst)
{
    __shared__ __align__(16) float s_m[2][MAXR][Ww];

    const int tid  = threadIdx.x;
    const int tile = blockIdx.x;   // 0..15
    const int inst = blockIdx.y;

    const int   s    = stride_p[0];       // 8
    const int   half = s >> 1;
    const int   im   = im_inds[inst];
    const int   lvl  = fpn_levels[inst];
    const float inv_soi = 1.0f / (float)(64 << lvl);  // SOI = 64*2^lvl exactly
    const float ixl = ilocs[inst * 2 + 0];
    const float iyl = ilocs[inst * 2 + 1];

    const int i0 = tile * TH;
    const int r_begin = ((i0 > 0) ? (i0 - 1) : 0) >> 1;
    int r_end = ((i0 + TH - 2) >> 1) + 1;
    if (r_end > Hh - 1) r_end = Hh - 1;
    const int nrows = r_end - r_begin + 1;   // 13 or 14

    // ---------- Phase A: head MLP at 200-res into LDS ----------
    const float* fbase = mask_feats + (size_t)im * 8 * Hh * Ww;
    const int npx = nrows * Ww;              // multiple of 4

    for (int g = tid * 4; g < npx; g += BLOCK * 4) {
        // prevent hoisting of all uniform weight loads across iterations
        asm volatile("" ::: "memory");

        const int lr = g / Ww;
        const int c  = g - lr * Ww;          // multiple of 4
        const int r  = r_begin + lr;

        // x[ch][pair]: pair0 = px{0,1}, pair1 = px{2,3}
        f32x2 x[10][2];
        {
            const float ry   = (iyl - (float)(r * s + half)) * inv_soi;
            const float step = -(float)s * inv_soi;
            const float cx0  = (ixl - (float)(c * s + half)) * inv_soi;
            x[0][0].x = cx0;            x[0][0].y = cx0 + step;
            x[0][1].x = cx0 + 2*step;   x[0][1].y = cx0 + 3*step;
            x[1][0] = splat2(ry);       x[1][1] = x[1][0];
            const float* fp = fbase + r * Ww + c;
            #pragma unroll
            for (int ch = 0; ch < 8; ch++) {
                const f32x4 f = *(const f32x4*)(fp + ch * (Hh * Ww));
                x[2 + ch][0].x = f.x; x[2 + ch][0].y = f.y;
                x[2 + ch][1].x = f.z; x[2 + ch][1].y = f.w;
            }
        }

        #pragma unroll 1
        for (int head = 0; head < 2; head++) {
            const float* P = wsf + (size_t)(inst * 2 + head) * HSTR;
            const f32x2 zero = splat2(0.0f);

            f32x2 h1[8][2];
            #pragma unroll
            for (int o = 0; o < 8; o++) {
                const f32x2* __restrict__ R = (const f32x2*)(P + o * 24);
                const f32x2 b = R[10];
                #pragma unroll
                for (int p = 0; p < 2; p++) {
                    f32x2 a = b;
                    a = pkfma(R[0], x[0][p], a);
                    a = pkfma(R[1], x[1][p], a);
                    a = pkfma(R[2], x[2][p], a);
                    a = pkfma(R[3], x[3][p], a);
                    a = pkfma(R[4], x[4][p], a);
                    a = pkfma(R[5], x[5][p], a);
                    a = pkfma(R[6], x[6][p], a);
                    a = pkfma(R[7], x[7][p], a);
                    a = pkfma(R[8], x[8][p], a);
                    a = pkfma(R[9], x[9][p], a);
                    h1[o][p] = __builtin_elementwise_max(a, zero);
                }
            }

            f32x2 h2[8][2];
            #pragma unroll
            for (int o = 0; o < 8; o++) {
                const f32x2* __restrict__ R = (const f32x2*)(P + 192 + o * 20);
                const f32x2 b = R[8];
                #pragma unroll
                for (int p = 0; p < 2; p++) {
                    f32x2 a = b;
                    a = pkfma(R[0], h1[0][p], a);
                    a = pkfma(R[1], h1[1][p], a);
                    a = pkfma(R[2], h1[2][p], a);
                    a = pkfma(R[3], h1[3][p], a);
                    a = pkfma(R[4], h1[4][p], a);
                    a = pkfma(R[5], h1[5][p], a);
                    a = pkfma(R[6], h1[6][p], a);
                    a = pkfma(R[7], h1[7][p], a);
                    h2[o][p] = __builtin_elementwise_max(a, zero);
                }
            }

            {
                const f32x2* __restrict__ R = (const f32x2*)(P + 352);
                const f32x2 b = R[8];
                f32x4 res;
                #pragma unroll
                for (int p = 0; p < 2; p++) {
                    f32x2 a = b;
                    a = pkfma(R[0], h2[0][p], a);
                    a = pkfma(R[1], h2[1][p], a);
                    a = pkfma(R[2], h2[2][p], a);
                    a = pkfma(R[3], h2[3][p], a);
                    a = pkfma(R[4], h2[4][p], a);
                    a = pkfma(R[5], h2[5][p], a);
                    a = pkfma(R[6], h2[6][p], a);
                    a = pkfma(R[7], h2[7][p], a);
                    res[2 * p]     = a.x;
                    res[2 * p + 1] = a.y;
                }
                *(f32x4*)(&s_m[head][lr][c]) = res;
            }
        }
    }

    __syncthreads();

    // ---------- Phase B: aligned_bilinear x2 + sigmoid ----------
    // One task = 8 output px from one aligned ds_read_b128 per source row
    // (conflict-free) + 1 guarded scalar left-neighbor.
    float* out0 = out + (size_t)inst * (OH * OW) + (size_t)i0 * OW;
    float* out1 = out0 + (size_t)n_inst * (OH * OW);

    const int NU = OW / 8;            // 50 groups per output row
    const int ntaskb = TH * NU;       // 1250
    for (int t = tid; t < ntaskb; t += BLOCK) {
        const int row = t / NU;
        const int u   = t - row * NU;
        const int i   = i0 + row;
        const int ip  = (i > 0) ? (i - 1) : 0;
        const int y0  = ip >> 1;
        const float wy = (ip & 1) ? 0.5f : 0.0f;
        const int lr0 = y0 - r_begin;
        const int r1c = (y0 + 1 <= Hh - 1) ? (y0 + 1) : (Hh - 1);
        const int lr1 = r1c - r_begin;

        #pragma unroll
        for (int head = 0; head < 2; head++) {
            const f32x4 A0 = *(const f32x4*)(&s_m[head][lr0][4 * u]);
            const f32x4 A1 = *(const f32x4*)(&s_m[head][lr1][4 * u]);
            float p0 = 0.0f, p1 = 0.0f;
            if (u > 0) {
                p0 = s_m[head][lr0][4 * u - 1];
                p1 = s_m[head][lr1][4 * u - 1];
            }
            f32x4 B;
            B.x = A0.x + (A1.x - A0.x) * wy;
            B.y = A0.y + (A1.y - A0.y) * wy;
            B.z = A0.z + (A1.z - A0.z) * wy;
            B.w = A0.w + (A1.w - A0.w) * wy;
            const float PB = p0 + (p1 - p0) * wy;

            float o[8];
            o[0] = (u > 0) ? 0.5f * (PB + B.x) : B.x;
            o[1] = B.x;
            o[2] = 0.5f * (B.x + B.y);
            o[3] = B.y;
            o[4] = 0.5f * (B.y + B.z);
            o[5] = B.z;
            o[6] = 0.5f * (B.z + B.w);
            o[7] = B.w;

            f32x4 lo, hi;
            #pragma unroll
            for (int k = 0; k < 4; k++) lo[k] = 1.0f / (1.0f + __expf(-o[k]));
            #pragma unroll
            for (int k = 0; k < 4; k++) hi[k] = 1.0f / (1.0f + __expf(-o[4 + k]));

            float* dst = (head ? out1 : out0) + row * OW + 8 * u;
            __builtin_nontemporal_store(lo, (f32x4*)dst);
            __builtin_nontemporal_store(hi, (f32x4*)(dst + 4));
        }
    }
}

extern "C" void kernel_launch(void* const* d_in, const int* in_sizes, int n_in,
                              void* d_out, int out_size, void* d_ws, size_t ws_size,
                              hipStream_t stream) {
    const float* mask_feats = (const float*)d_in[0];
    const float* mparams    = (const float*)d_in[1];
    const float* bparams    = (const float*)d_in[2];
    const float* ilocs      = (const float*)d_in[3];
    const int*   im_inds    = (const int*)d_in[4];
    const int*   fpn_levels = (const int*)d_in[5];
    const int*   stride_p   = (const int*)d_in[6];
    float* out = (float*)d_out;
    float* wsf = (float*)d_ws;   // needs 128*2*384*4 = 393,216 B

    const int n_inst = in_sizes[1] / NP;      // 128

    hipLaunchKernelGGL(repack_params, dim3(n_inst), dim3(BLOCK), 0, stream,
                       mparams, bparams, wsf);

    dim3 grid(OH / TH, n_inst);               // (16, 128)
    hipLaunchKernelGGL(dmh_fused, grid, dim3(BLOCK), 0, stream,
                       mask_feats, wsf, ilocs,
                       im_inds, fpn_levels, stride_p, out, n_inst);
}